// Round 3
// baseline (735.301 us; speedup 1.0000x reference)
//
#include <hip/hip_runtime.h>
#include <cstdint>
#include <cstddef>

typedef unsigned short u16;
typedef unsigned int u32;

typedef __bf16 bf16x8 __attribute__((ext_vector_type(8)));
typedef float f32x4 __attribute__((ext_vector_type(4)));
typedef u32 u32x4 __attribute__((ext_vector_type(4)));

// ---- bf16 <-> f32 helpers (raw-bit) ----
__device__ inline float bf2f(u16 u) {
    union { u32 i; float f; } c; c.i = ((u32)u) << 16; return c.f;
}
__device__ inline u16 f2bf(float f) {
    union { float f; u32 i; } c; c.f = f;
    u32 u = c.i;
    return (u16)((u + 0x7fffu + ((u >> 16) & 1u)) >> 16);  // RNE
}
__device__ inline f32x4 mfma16(u32x4 a, u32x4 b, f32x4 c) {
    return __builtin_amdgcn_mfma_f32_16x16x32_bf16(
        __builtin_bit_cast(bf16x8, a), __builtin_bit_cast(bf16x8, b), c, 0, 0, 0);
}
// 8 consecutive f32 -> 8 bf16 packed in u32x4 (little-endian: low u16 = even idx)
__device__ inline u32x4 cvt8(const float* p) {
    f32x4 a = *(const f32x4*)p, b = *(const f32x4*)(p + 4);
    u32x4 v;
    v[0] = (u32)f2bf(a[0]) | ((u32)f2bf(a[1]) << 16);
    v[1] = (u32)f2bf(a[2]) | ((u32)f2bf(a[3]) << 16);
    v[2] = (u32)f2bf(b[0]) | ((u32)f2bf(b[1]) << 16);
    v[3] = (u32)f2bf(b[2]) | ((u32)f2bf(b[3]) << 16);
    return v;
}

// =====================================================================
// Kernel 0: dtype detector. bf16 data: ~100% of u16s have exp in [115,133];
// fp32 data reinterpreted as u16 pairs: ~54% (low halves uniform). flag=1 -> bf16.
// (Round-1 NaN forensics => inputs are fp32; detector kept as insurance.)
// =====================================================================
__global__ __launch_bounds__(64) void k_detect(const u16* __restrict__ x, u32* __restrict__ flag)
{
    const int lane = threadIdx.x;
    int cnt = 0;
#pragma unroll
    for (int i = 0; i < 4; i++) {
        u32 e = (x[lane * 4 + i] >> 7) & 0xFF;
        cnt += (e >= 115 && e <= 133) ? 1 : 0;
    }
#pragma unroll
    for (int off = 1; off < 64; off <<= 1) cnt += __shfl_xor(cnt, off);
    if (lane == 0) *flag = (cnt >= 192) ? 1u : 0u;
}

// =====================================================================
// Kernel 1: transpose weights. WT[c][k] (2304x768) <- [Wq | Wkv][k][c];
//           WoT[c][k] (768x768) <- Wo[k][c].  Output always bf16.
// =====================================================================
__global__ __launch_bounds__(256) void k_transpose_w(
    const void* __restrict__ Wq, const void* __restrict__ Wkv, const void* __restrict__ Wo,
    u16* __restrict__ WT, u16* __restrict__ WoT, const u32* __restrict__ flag)
{
    const bool isb = (*flag != 0);
    __shared__ __align__(16) u16 t[64][72];
    const int z = blockIdx.z;
    const void* src; u16* dst; int C;
    if (z == 0)      { src = Wq;  dst = WT;             C = 768;  }
    else if (z == 1) { src = Wkv; dst = WT + 768 * 768; C = 1536; }
    else             { src = Wo;  dst = WoT;            C = 768;  }
    const int c0 = blockIdx.y * 64;
    if (c0 >= C) return;
    const int k0 = blockIdx.x * 64;
    const int tid = threadIdx.x;
    const int r = tid >> 3, cc = (tid & 7) * 8;
    if (isb) {
        const u16* s = (const u16*)src;
        for (int rr = r; rr < 64; rr += 32)
            *(u32x4*)&t[rr][cc] = *(const u32x4*)(s + (size_t)(k0 + rr) * C + c0 + cc);
    } else {
        const float* s = (const float*)src;
        for (int rr = r; rr < 64; rr += 32)
            *(u32x4*)&t[rr][cc] = cvt8(s + (size_t)(k0 + rr) * C + c0 + cc);
    }
    __syncthreads();
    const int kk = (tid & 7) * 8;
    for (int ccc = tid >> 3; ccc < 64; ccc += 32) {
        __align__(16) u16 tmp[8];
#pragma unroll
        for (int s = 0; s < 8; s++) tmp[s] = t[kk + s][ccc];
        *(u32x4*)(dst + (size_t)(c0 + ccc) * 768 + k0 + kk) = *(u32x4*)tmp;
    }
}

// =====================================================================
// Kernel 3: transpose v [B*H, 1024, 64] -> vt [B*H, 64, 1024] (bf16 in/out)
// =====================================================================
__global__ __launch_bounds__(256) void k_transpose_v(
    const u16* __restrict__ v, u16* __restrict__ vt)
{
    __shared__ __align__(16) u16 t[64][72];
    const int bh = blockIdx.z;
    const int t0 = blockIdx.x * 64;
    const int tid = threadIdx.x;
    const int r = tid >> 3, cc = (tid & 7) * 8;
    for (int rr = r; rr < 64; rr += 32)
        *(u32x4*)&t[rr][cc] = *(const u32x4*)(v + ((size_t)bh * 1024 + t0 + rr) * 64 + cc);
    __syncthreads();
    const int kk = (tid & 7) * 8;
    for (int ccc = tid >> 3; ccc < 64; ccc += 32) {
        __align__(16) u16 tmp[8];
#pragma unroll
        for (int s = 0; s < 8; s++) tmp[s] = t[kk + s][ccc];
        *(u32x4*)(vt + ((size_t)bh * 64 + ccc) * 1024 + t0 + kk) = *(u32x4*)tmp;
    }
}

// =====================================================================
// Kernel 2: fused QKV GEMM. X[8192,768] @ W -> q,k,v in [B,H,N,DH].
// 64x64 tile, 4 waves each 32x32, MFMA 16x16x32 bf16, BK=32.
// A (X) staging is dual-dtype; B (WT) is always bf16.
// =====================================================================
__global__ __launch_bounds__(256) void k_gemm_qkv(
    const void* __restrict__ X, const u16* __restrict__ WT,
    u16* __restrict__ qb, u16* __restrict__ kb, u16* __restrict__ vb,
    const u32* __restrict__ flag)
{
    const bool isb = (*flag != 0);
    __shared__ __align__(16) u16 As[64][40];
    __shared__ __align__(16) u16 Bs[64][40];
    const int tid = threadIdx.x;
    const int wave = tid >> 6, lane = tid & 63, quad = lane >> 4, l15 = lane & 15;
    const int wr = wave >> 1, wc = wave & 1;
    const int m0 = blockIdx.y * 64, c0 = blockIdx.x * 64;
    f32x4 acc[2][2];
#pragma unroll
    for (int i = 0; i < 2; i++)
#pragma unroll
        for (int j = 0; j < 2; j++) acc[i][j] = (f32x4){0.f, 0.f, 0.f, 0.f};
    const int ar = tid >> 2, akc = (tid & 3) * 8;
    const u16*   a16 = (const u16*)X   + (size_t)(m0 + ar) * 768 + akc;
    const float* a32 = (const float*)X + (size_t)(m0 + ar) * 768 + akc;
    const u16* bptr = WT + (size_t)(c0 + ar) * 768 + akc;
    for (int k0 = 0; k0 < 768; k0 += 32) {
        u32x4 av = isb ? *(const u32x4*)(a16 + k0) : cvt8(a32 + k0);
        u32x4 bv = *(const u32x4*)(bptr + k0);
        __syncthreads();
        *(u32x4*)&As[ar][akc] = av;
        *(u32x4*)&Bs[ar][akc] = bv;
        __syncthreads();
#pragma unroll
        for (int mi = 0; mi < 2; mi++) {
            u32x4 af = *(const u32x4*)&As[wr * 32 + mi * 16 + l15][quad * 8];
#pragma unroll
            for (int ni = 0; ni < 2; ni++) {
                u32x4 bf = *(const u32x4*)&Bs[wc * 32 + ni * 16 + l15][quad * 8];
                acc[mi][ni] = mfma16(af, bf, acc[mi][ni]);
            }
        }
    }
#pragma unroll
    for (int mi = 0; mi < 2; mi++) {
#pragma unroll
        for (int ni = 0; ni < 2; ni++) {
            const int c = c0 + wc * 32 + ni * 16 + l15;
            const int sector = c / 768, hc = c % 768;
            const int h = hc >> 6, d = hc & 63;
            u16* dst = sector == 0 ? qb : (sector == 1 ? kb : vb);
#pragma unroll
            for (int r = 0; r < 4; r++) {
                const int tok = m0 + wr * 32 + mi * 16 + quad * 4 + r;
                const int b = tok >> 10, n = tok & 1023;
                dst[(((size_t)b * 12 + h) * 1024 + n) * 64 + d] = f2bf(acc[mi][ni][r]);
            }
        }
    }
}

// =====================================================================
// Kernel 5: output GEMM. o[8192,768] @ Wo + bo -> out (FP32 — round-2 finding:
// harness reads d_out as float32; bf16 store produced the 0.0586 interleave error)
// =====================================================================
__global__ __launch_bounds__(256) void k_gemm_out(
    const u16* __restrict__ O, const u16* __restrict__ WoT, const void* __restrict__ bo,
    float* __restrict__ out, const u32* __restrict__ flag)
{
    const bool isb = (*flag != 0);
    __shared__ __align__(16) u16 As[64][40];
    __shared__ __align__(16) u16 Bs[64][40];
    const int tid = threadIdx.x;
    const int wave = tid >> 6, lane = tid & 63, quad = lane >> 4, l15 = lane & 15;
    const int wr = wave >> 1, wc = wave & 1;
    const int m0 = blockIdx.y * 64, c0 = blockIdx.x * 64;
    f32x4 acc[2][2];
#pragma unroll
    for (int i = 0; i < 2; i++)
#pragma unroll
        for (int j = 0; j < 2; j++) acc[i][j] = (f32x4){0.f, 0.f, 0.f, 0.f};
    const int ar = tid >> 2, akc = (tid & 3) * 8;
    const u16* aptr = O   + (size_t)(m0 + ar) * 768 + akc;
    const u16* bptr = WoT + (size_t)(c0 + ar) * 768 + akc;
    for (int k0 = 0; k0 < 768; k0 += 32) {
        u32x4 av = *(const u32x4*)(aptr + k0);
        u32x4 bv = *(const u32x4*)(bptr + k0);
        __syncthreads();
        *(u32x4*)&As[ar][akc] = av;
        *(u32x4*)&Bs[ar][akc] = bv;
        __syncthreads();
#pragma unroll
        for (int mi = 0; mi < 2; mi++) {
            u32x4 af = *(const u32x4*)&As[wr * 32 + mi * 16 + l15][quad * 8];
#pragma unroll
            for (int ni = 0; ni < 2; ni++) {
                u32x4 bf = *(const u32x4*)&Bs[wc * 32 + ni * 16 + l15][quad * 8];
                acc[mi][ni] = mfma16(af, bf, acc[mi][ni]);
            }
        }
    }
#pragma unroll
    for (int mi = 0; mi < 2; mi++) {
#pragma unroll
        for (int ni = 0; ni < 2; ni++) {
            const int c = c0 + wc * 32 + ni * 16 + l15;
            const float biasv = isb ? bf2f(((const u16*)bo)[c]) : ((const float*)bo)[c];
#pragma unroll
            for (int r = 0; r < 4; r++) {
                const int tok = m0 + wr * 32 + mi * 16 + quad * 4 + r;
                out[(size_t)tok * 768 + c] = acc[mi][ni][r] + biasv;
            }
        }
    }
}

// =====================================================================
// Kernel 4: talking-heads attention.
// Grid (64 q-tiles of 16 rows, 8 batch), 768 threads = 12 waves (wave = head).
// Two-pass softmax (no max subtraction: mixed logits ~ N(0,1/12), exp-safe).
// LDS: 48KB score/prob buffer; bf16 amix (A-layout) aliases it (50.3KB total).
// =====================================================================
__global__ __launch_bounds__(768) void k_attn(
    const u16* __restrict__ qb, const u16* __restrict__ kb, const u16* __restrict__ vt,
    const void* __restrict__ mixpre, const void* __restrict__ mixpost,
    u16* __restrict__ ob, const u32* __restrict__ flag)
{
    __shared__ __align__(16) float sbuf[12 * 16 * 64];   // 48KB scores/probs
    __shared__ float mpre[144], mpost[144];
    u16* amix = (u16*)sbuf;                              // aliases sbuf (27.6KB used)
    const bool isb = (*flag != 0);
    const int tid = threadIdx.x;
    const int w = tid >> 6, lane = tid & 63, quad = lane >> 4, l15 = lane & 15;
    if (tid < 144) {
        mpre[tid]  = isb ? bf2f(((const u16*)mixpre)[tid])  : ((const float*)mixpre)[tid];
        mpost[tid] = isb ? bf2f(((const u16*)mixpost)[tid]) : ((const float*)mixpost)[tid];
    }
    const int b = blockIdx.y, i0 = blockIdx.x * 16;
    const u16* qh = qb + (((size_t)b * 12 + w) * 1024 + i0) * 64;
    u32x4 aq[2];
#pragma unroll
    for (int kc = 0; kc < 2; kc++)
        aq[kc] = *(const u32x4*)(qh + l15 * 64 + kc * 32 + quad * 8);
    const u16* kh = kb + ((size_t)b * 12 + w) * 1024 * 64;
    const u16* vh = vt + ((size_t)b * 12 + w) * 64 * 1024;

    float lsum[16];
#pragma unroll
    for (int i = 0; i < 16; i++) lsum[i] = 0.f;

    // ---------------- pass 1: softmax denominators ----------------
    for (int jt = 0; jt < 16; jt++) {
        const int j0 = jt * 64;
        f32x4 sc[4];
#pragma unroll
        for (int nt = 0; nt < 4; nt++) {
            f32x4 a = (f32x4){0.f, 0.f, 0.f, 0.f};
#pragma unroll
            for (int kc = 0; kc < 2; kc++) {
                u32x4 bfr = *(const u32x4*)(kh + (size_t)(j0 + nt * 16 + l15) * 64 + kc * 32 + quad * 8);
                a = mfma16(aq[kc], bfr, a);
            }
            sc[nt] = a;
        }
        __syncthreads();   // prior iteration's sbuf reads done
#pragma unroll
        for (int nt = 0; nt < 4; nt++)
#pragma unroll
            for (int r = 0; r < 4; r++)
                sbuf[w * 1024 + (quad * 4 + r) * 64 + nt * 16 + l15] = sc[nt][r] * 0.125f;
        __syncthreads();
#pragma unroll
        for (int i = 0; i < 16; i++) {
            float d2 = 0.f;
#pragma unroll
            for (int h = 0; h < 12; h++) d2 += mpre[h * 12 + w] * sbuf[h * 1024 + i * 64 + lane];
            lsum[i] += __expf(d2);
        }
    }
    float invl[16];
#pragma unroll
    for (int i = 0; i < 16; i++) {
        float s = lsum[i];
#pragma unroll
        for (int off = 1; off < 64; off <<= 1) s += __shfl_xor(s, off);
        invl[i] = 1.f / s;
    }

    f32x4 oacc[4];
#pragma unroll
    for (int nt = 0; nt < 4; nt++) oacc[nt] = (f32x4){0.f, 0.f, 0.f, 0.f};

    // ---------------- pass 2: probs, post-mix, PV ----------------
    for (int jt = 0; jt < 16; jt++) {
        const int j0 = jt * 64;
        f32x4 sc[4];
#pragma unroll
        for (int nt = 0; nt < 4; nt++) {
            f32x4 a = (f32x4){0.f, 0.f, 0.f, 0.f};
#pragma unroll
            for (int kc = 0; kc < 2; kc++) {
                u32x4 bfr = *(const u32x4*)(kh + (size_t)(j0 + nt * 16 + l15) * 64 + kc * 32 + quad * 8);
                a = mfma16(aq[kc], bfr, a);
            }
            sc[nt] = a;
        }
        __syncthreads();   // (A) prior iteration's amix fragment reads done
#pragma unroll
        for (int nt = 0; nt < 4; nt++)
#pragma unroll
            for (int r = 0; r < 4; r++)
                sbuf[w * 1024 + (quad * 4 + r) * 64 + nt * 16 + l15] = sc[nt][r] * 0.125f;
        __syncthreads();   // (B) scores visible
        float p[16];
#pragma unroll
        for (int i = 0; i < 16; i++) {
            float d2 = 0.f;
#pragma unroll
            for (int h = 0; h < 12; h++) d2 += mpre[h * 12 + w] * sbuf[h * 1024 + i * 64 + lane];
            p[i] = __expf(d2) * invl[i];
        }
        __syncthreads();   // (C) all score reads done; sbuf becomes probs
#pragma unroll
        for (int i = 0; i < 16; i++) sbuf[w * 1024 + i * 64 + lane] = p[i];
        __syncthreads();   // (D) probs visible
#pragma unroll
        for (int i = 0; i < 16; i++) {
            float a = 0.f;
#pragma unroll
            for (int g = 0; g < 12; g++) a += mpost[g * 12 + w] * sbuf[g * 1024 + i * 64 + lane];
            p[i] = a;      // reuse regs: post-mixed probs
        }
        __syncthreads();   // (E) all prob reads done; sbuf low region becomes amix
#pragma unroll
        for (int i = 0; i < 16; i++) amix[w * 1152 + i * 72 + lane] = f2bf(p[i]);
        __syncthreads();   // (F) amix visible
#pragma unroll
        for (int kc = 0; kc < 2; kc++) {
            u32x4 af = *(const u32x4*)&amix[w * 1152 + l15 * 72 + kc * 32 + quad * 8];
#pragma unroll
            for (int nt = 0; nt < 4; nt++) {
                u32x4 vf = *(const u32x4*)(vh + (size_t)(nt * 16 + l15) * 1024 + j0 + kc * 32 + quad * 8);
                oacc[nt] = mfma16(af, vf, oacc[nt]);
            }
        }
    }
#pragma unroll
    for (int nt = 0; nt < 4; nt++)
#pragma unroll
        for (int r = 0; r < 4; r++)
            ob[((size_t)b * 1024 + i0 + quad * 4 + r) * 768 + w * 64 + nt * 16 + l15] =
                f2bf(oacc[nt][r]);
}

// =====================================================================
extern "C" void kernel_launch(void* const* d_in, const int* in_sizes, int n_in,
                              void* d_out, int out_size, void* d_ws, size_t ws_size,
                              hipStream_t stream)
{
    float* out = (float*)d_out;

    u32* flag = (u32*)d_ws;
    u16* base = (u16*)d_ws + 128;          // 256B for flag, keep 16B alignment
    u16* WT   = base;                      // 2304*768
    u16* WoT  = WT  + 2304 * 768;          // 768*768
    u16* qb   = WoT + 768 * 768;           // 6291456
    u16* kb   = qb  + 6291456;             // 6291456
    u16* vtb  = kb  + 6291456;             // 6291456
    u16* obuf = vtb + 6291456;             // 6291456 (aliases vb: v dead after transpose)
    u16* vb   = obuf;

    k_detect     <<<dim3(1), 64,  0, stream>>>((const u16*)d_in[0], flag);
    k_transpose_w<<<dim3(12, 24, 3), 256, 0, stream>>>(d_in[1], d_in[2], d_in[5], WT, WoT, flag);
    k_gemm_qkv   <<<dim3(36, 128),   256, 0, stream>>>(d_in[0], WT, qb, kb, vb, flag);
    k_transpose_v<<<dim3(16, 1, 96), 256, 0, stream>>>(vb, vtb);
    k_attn       <<<dim3(64, 8),     768, 0, stream>>>(qb, kb, vtb, d_in[3], d_in[4], obuf, flag);
    k_gemm_out   <<<dim3(12, 128),   256, 0, stream>>>(obuf, WoT, d_in[6], out, flag);
}

// Round 4
// 573.484 us; speedup vs baseline: 1.2822x; 1.2822x over previous
//
#include <hip/hip_runtime.h>
#include <cstdint>
#include <cstddef>

typedef unsigned short u16;
typedef unsigned int u32;

typedef __bf16 bf16x8 __attribute__((ext_vector_type(8)));
typedef float f32x4 __attribute__((ext_vector_type(4)));
typedef u32 u32x4 __attribute__((ext_vector_type(4)));

__device__ inline float bf2f(u16 u) {
    union { u32 i; float f; } c; c.i = ((u32)u) << 16; return c.f;
}
__device__ inline u16 f2bf(float f) {
    union { float f; u32 i; } c; c.f = f;
    u32 u = c.i;
    return (u16)((u + 0x7fffu + ((u >> 16) & 1u)) >> 16);  // RNE
}
__device__ inline f32x4 mfma16(u32x4 a, u32x4 b, f32x4 c) {
    return __builtin_amdgcn_mfma_f32_16x16x32_bf16(
        __builtin_bit_cast(bf16x8, a), __builtin_bit_cast(bf16x8, b), c, 0, 0, 0);
}
__device__ inline u32x4 cvt8(const float* p) {
    f32x4 a = *(const f32x4*)p, b = *(const f32x4*)(p + 4);
    u32x4 v;
    v[0] = (u32)f2bf(a[0]) | ((u32)f2bf(a[1]) << 16);
    v[1] = (u32)f2bf(a[2]) | ((u32)f2bf(a[3]) << 16);
    v[2] = (u32)f2bf(b[0]) | ((u32)f2bf(b[1]) << 16);
    v[3] = (u32)f2bf(b[2]) | ((u32)f2bf(b[3]) << 16);
    return v;
}

// ===================== dtype detector (round-1 forensics: inputs fp32) ========
__global__ __launch_bounds__(64) void k_detect(const u16* __restrict__ x, u32* __restrict__ flag)
{
    const int lane = threadIdx.x;
    int cnt = 0;
#pragma unroll
    for (int i = 0; i < 4; i++) {
        u32 e = (x[lane * 4 + i] >> 7) & 0xFF;
        cnt += (e >= 115 && e <= 133) ? 1 : 0;
    }
#pragma unroll
    for (int off = 1; off < 64; off <<= 1) cnt += __shfl_xor(cnt, off);
    if (lane == 0) *flag = (cnt >= 192) ? 1u : 0u;
}

// ===================== weight transpose (unchanged, validated) ================
__global__ __launch_bounds__(256) void k_transpose_w(
    const void* __restrict__ Wq, const void* __restrict__ Wkv, const void* __restrict__ Wo,
    u16* __restrict__ WT, u16* __restrict__ WoT, const u32* __restrict__ flag)
{
    const bool isb = (*flag != 0);
    __shared__ __align__(16) u16 t[64][72];
    const int z = blockIdx.z;
    const void* src; u16* dst; int C;
    if (z == 0)      { src = Wq;  dst = WT;             C = 768;  }
    else if (z == 1) { src = Wkv; dst = WT + 768 * 768; C = 1536; }
    else             { src = Wo;  dst = WoT;            C = 768;  }
    const int c0 = blockIdx.y * 64;
    if (c0 >= C) return;
    const int k0 = blockIdx.x * 64;
    const int tid = threadIdx.x;
    const int r = tid >> 3, cc = (tid & 7) * 8;
    if (isb) {
        const u16* s = (const u16*)src;
        for (int rr = r; rr < 64; rr += 32)
            *(u32x4*)&t[rr][cc] = *(const u32x4*)(s + (size_t)(k0 + rr) * C + c0 + cc);
    } else {
        const float* s = (const float*)src;
        for (int rr = r; rr < 64; rr += 32)
            *(u32x4*)&t[rr][cc] = cvt8(s + (size_t)(k0 + rr) * C + c0 + cc);
    }
    __syncthreads();
    const int kk = (tid & 7) * 8;
    for (int ccc = tid >> 3; ccc < 64; ccc += 32) {
        __align__(16) u16 tmp[8];
#pragma unroll
        for (int s = 0; s < 8; s++) tmp[s] = t[kk + s][ccc];
        *(u32x4*)(dst + (size_t)(c0 + ccc) * 768 + k0 + kk) = *(u32x4*)tmp;
    }
}

// ===================== v transpose (unchanged, validated) =====================
__global__ __launch_bounds__(256) void k_transpose_v(
    const u16* __restrict__ v, u16* __restrict__ vt)
{
    __shared__ __align__(16) u16 t[64][72];
    const int bh = blockIdx.z;
    const int t0 = blockIdx.x * 64;
    const int tid = threadIdx.x;
    const int r = tid >> 3, cc = (tid & 7) * 8;
    for (int rr = r; rr < 64; rr += 32)
        *(u32x4*)&t[rr][cc] = *(const u32x4*)(v + ((size_t)bh * 1024 + t0 + rr) * 64 + cc);
    __syncthreads();
    const int kk = (tid & 7) * 8;
    for (int ccc = tid >> 3; ccc < 64; ccc += 32) {
        __align__(16) u16 tmp[8];
#pragma unroll
        for (int s = 0; s < 8; s++) tmp[s] = t[kk + s][ccc];
        *(u32x4*)(vt + ((size_t)bh * 64 + ccc) * 1024 + t0 + kk) = *(u32x4*)tmp;
    }
}

// ===================== QKV GEMM (unchanged, validated) ========================
__global__ __launch_bounds__(256) void k_gemm_qkv(
    const void* __restrict__ X, const u16* __restrict__ WT,
    u16* __restrict__ qb, u16* __restrict__ kb, u16* __restrict__ vb,
    const u32* __restrict__ flag)
{
    const bool isb = (*flag != 0);
    __shared__ __align__(16) u16 As[64][40];
    __shared__ __align__(16) u16 Bs[64][40];
    const int tid = threadIdx.x;
    const int wave = tid >> 6, lane = tid & 63, quad = lane >> 4, l15 = lane & 15;
    const int wr = wave >> 1, wc = wave & 1;
    const int m0 = blockIdx.y * 64, c0 = blockIdx.x * 64;
    f32x4 acc[2][2];
#pragma unroll
    for (int i = 0; i < 2; i++)
#pragma unroll
        for (int j = 0; j < 2; j++) acc[i][j] = (f32x4){0.f, 0.f, 0.f, 0.f};
    const int ar = tid >> 2, akc = (tid & 3) * 8;
    const u16*   a16 = (const u16*)X   + (size_t)(m0 + ar) * 768 + akc;
    const float* a32 = (const float*)X + (size_t)(m0 + ar) * 768 + akc;
    const u16* bptr = WT + (size_t)(c0 + ar) * 768 + akc;
    for (int k0 = 0; k0 < 768; k0 += 32) {
        u32x4 av = isb ? *(const u32x4*)(a16 + k0) : cvt8(a32 + k0);
        u32x4 bv = *(const u32x4*)(bptr + k0);
        __syncthreads();
        *(u32x4*)&As[ar][akc] = av;
        *(u32x4*)&Bs[ar][akc] = bv;
        __syncthreads();
#pragma unroll
        for (int mi = 0; mi < 2; mi++) {
            u32x4 af = *(const u32x4*)&As[wr * 32 + mi * 16 + l15][quad * 8];
#pragma unroll
            for (int ni = 0; ni < 2; ni++) {
                u32x4 bf = *(const u32x4*)&Bs[wc * 32 + ni * 16 + l15][quad * 8];
                acc[mi][ni] = mfma16(af, bf, acc[mi][ni]);
            }
        }
    }
#pragma unroll
    for (int mi = 0; mi < 2; mi++) {
#pragma unroll
        for (int ni = 0; ni < 2; ni++) {
            const int c = c0 + wc * 32 + ni * 16 + l15;
            const int sector = c / 768, hc = c % 768;
            const int h = hc >> 6, d = hc & 63;
            u16* dst = sector == 0 ? qb : (sector == 1 ? kb : vb);
#pragma unroll
            for (int r = 0; r < 4; r++) {
                const int tok = m0 + wr * 32 + mi * 16 + quad * 4 + r;
                const int b = tok >> 10, n = tok & 1023;
                dst[(((size_t)b * 12 + h) * 1024 + n) * 64 + d] = f2bf(acc[mi][ni][r]);
            }
        }
    }
}

// ===================== output GEMM (unchanged, validated; fp32 out) ===========
__global__ __launch_bounds__(256) void k_gemm_out(
    const u16* __restrict__ O, const u16* __restrict__ WoT, const void* __restrict__ bo,
    float* __restrict__ out, const u32* __restrict__ flag)
{
    const bool isb = (*flag != 0);
    __shared__ __align__(16) u16 As[64][40];
    __shared__ __align__(16) u16 Bs[64][40];
    const int tid = threadIdx.x;
    const int wave = tid >> 6, lane = tid & 63, quad = lane >> 4, l15 = lane & 15;
    const int wr = wave >> 1, wc = wave & 1;
    const int m0 = blockIdx.y * 64, c0 = blockIdx.x * 64;
    f32x4 acc[2][2];
#pragma unroll
    for (int i = 0; i < 2; i++)
#pragma unroll
        for (int j = 0; j < 2; j++) acc[i][j] = (f32x4){0.f, 0.f, 0.f, 0.f};
    const int ar = tid >> 2, akc = (tid & 3) * 8;
    const u16* aptr = O   + (size_t)(m0 + ar) * 768 + akc;
    const u16* bptr = WoT + (size_t)(c0 + ar) * 768 + akc;
    for (int k0 = 0; k0 < 768; k0 += 32) {
        u32x4 av = *(const u32x4*)(aptr + k0);
        u32x4 bv = *(const u32x4*)(bptr + k0);
        __syncthreads();
        *(u32x4*)&As[ar][akc] = av;
        *(u32x4*)&Bs[ar][akc] = bv;
        __syncthreads();
#pragma unroll
        for (int mi = 0; mi < 2; mi++) {
            u32x4 af = *(const u32x4*)&As[wr * 32 + mi * 16 + l15][quad * 8];
#pragma unroll
            for (int ni = 0; ni < 2; ni++) {
                u32x4 bf = *(const u32x4*)&Bs[wc * 32 + ni * 16 + l15][quad * 8];
                acc[mi][ni] = mfma16(af, bf, acc[mi][ni]);
            }
        }
    }
#pragma unroll
    for (int mi = 0; mi < 2; mi++) {
#pragma unroll
        for (int ni = 0; ni < 2; ni++) {
            const int c = c0 + wc * 32 + ni * 16 + l15;
            const float biasv = isb ? bf2f(((const u16*)bo)[c]) : ((const float*)bo)[c];
#pragma unroll
            for (int r = 0; r < 4; r++) {
                const int tok = m0 + wr * 32 + mi * 16 + quad * 4 + r;
                out[(size_t)tok * 768 + c] = acc[mi][ni][r] + biasv;
            }
        }
    }
}

// =====================================================================
// k_attn v2: talking-heads attention with MFMA-ized head mixing.
// Grid (64 q-tiles of 16 rows, 8 batch), 768 threads = 12 waves.
// QK^T per head-wave -> scores to SP[n=(i,j)][h] bf16 (pitch 18).
// Mixing: one 16x16x32 MFMA per 16-wide n-slice; K=32 = 12 heads + 4
// zeroed pad cols + 16 register-zeros (quads 2,3 feed 0 for A and B).
// Slice s owned by wave (s%12); slice rows of SP are wave-exclusive
// between barriers, so probs overwrite scores in place (lgkmcnt only).
// Two-pass softmax; denominators via shuffle + 4KB red (aliases Abuf).
// =====================================================================
__global__ __launch_bounds__(768) void k_attn(
    const u16* __restrict__ qb, const u16* __restrict__ kb, const u16* __restrict__ vt,
    const void* __restrict__ mixpre, const void* __restrict__ mixpost,
    u16* __restrict__ ob, const u32* __restrict__ flag)
{
    __shared__ __align__(16) u16 SP[1024 * 18];     // 36,864 B  scores/probs [n][h]
    __shared__ __align__(16) u16 Abuf[12 * 1160];   // 27,840 B  amix A-layout [g2][i][72]
    u32* SP32 = (u32*)SP;
    float* red = (float*)Abuf;                      // 4KB reduction scratch (pass-1 only)

    const bool isb = (*flag != 0);
    const int tid = threadIdx.x;
    const int w = tid >> 6, lane = tid & 63, quad = lane >> 4, l15 = lane & 15;
    const int b = blockIdx.y, i0 = blockIdx.x * 16;

    // zero pad head-cols 12..15 (u32 cols 6,7) once; 0xNaN-proofing for premix
    for (int n = tid; n < 1024; n += 768) { SP32[n * 9 + 6] = 0; SP32[n * 9 + 7] = 0; }

    // mix matrices as MFMA A-fragments: A[m=g(l15)][k=h(quad*8+j)] = mix[h][g]
    u32x4 apre = (u32x4){0, 0, 0, 0}, apost = (u32x4){0, 0, 0, 0};
    if (quad < 2 && l15 < 12) {
#pragma unroll
        for (int j = 0; j < 8; j++) {
            const int h = quad * 8 + j;
            u16 v1 = 0, v2 = 0;
            if (h < 12) {
                v1 = isb ? ((const u16*)mixpre)[h * 12 + l15]  : f2bf(((const float*)mixpre)[h * 12 + l15]);
                v2 = isb ? ((const u16*)mixpost)[h * 12 + l15] : f2bf(((const float*)mixpost)[h * 12 + l15]);
            }
            apre[j >> 1]  |= ((u32)v1) << ((j & 1) * 16);
            apost[j >> 1] |= ((u32)v2) << ((j & 1) * 16);
        }
    }

    const u16* qh = qb + (((size_t)b * 12 + w) * 1024 + i0) * 64;
    u32x4 aq[2];
#pragma unroll
    for (int kc = 0; kc < 2; kc++)
        aq[kc] = *(const u32x4*)(qh + l15 * 64 + kc * 32 + quad * 8);
    const u16* kh = kb + ((size_t)b * 12 + w) * 1024 * 64;
    const u16* vh = vt + ((size_t)b * 12 + w) * 64 * 1024;

    // ---------------- pass 1: softmax denominators ----------------
    f32x4 part[6];
#pragma unroll
    for (int t = 0; t < 6; t++) part[t] = (f32x4){0.f, 0.f, 0.f, 0.f};

    for (int jt = 0; jt < 16; jt++) {
        const int j0 = jt * 64;
        f32x4 sc[4];
#pragma unroll
        for (int nt = 0; nt < 4; nt++) {
            f32x4 a = (f32x4){0.f, 0.f, 0.f, 0.f};
#pragma unroll
            for (int kc = 0; kc < 2; kc++) {
                u32x4 bfr = *(const u32x4*)(kh + (size_t)(j0 + nt * 16 + l15) * 64 + kc * 32 + quad * 8);
                a = mfma16(aq[kc], bfr, a);
            }
            sc[nt] = a;
        }
        __syncthreads();   // prior jt premix reads done
#pragma unroll
        for (int nt = 0; nt < 4; nt++)
#pragma unroll
            for (int r = 0; r < 4; r++)
                SP[((quad * 4 + r) * 64 + nt * 16 + l15) * 18 + w] = f2bf(sc[nt][r] * 0.125f);
        __syncthreads();   // scores visible
#pragma unroll
        for (int t = 0; t < 6; t++) {
            const int s = w + 12 * t;
            if (s < 64) {
                u32x4 bfr = (u32x4){0, 0, 0, 0};
                if (quad < 2) {
                    const u32* p = SP32 + (s * 16 + l15) * 9 + quad * 4;
                    bfr[0] = p[0]; bfr[1] = p[1]; bfr[2] = p[2]; bfr[3] = p[3];
                }
                f32x4 d = mfma16(apre, bfr, (f32x4){0.f, 0.f, 0.f, 0.f});
#pragma unroll
                for (int r = 0; r < 4; r++) part[t][r] += __expf(d[r]);
            }
        }
    }
    __syncthreads();       // last premix reads done (SP free for pass-2)
    // cross-lane j reduction; red[(i*16+g)*4 + jq] (aliases Abuf, dead in pass 1)
#pragma unroll
    for (int t = 0; t < 6; t++) {
        const int s = w + 12 * t;
        if (s < 64) {
#pragma unroll
            for (int r = 0; r < 4; r++) {
                float v = part[t][r];
#pragma unroll
                for (int off = 1; off < 16; off <<= 1) v += __shfl_xor(v, off);
                if (l15 == 0) red[(((s >> 2) * 16) + quad * 4 + r) * 4 + (s & 3)] = v;
            }
        }
    }
    __syncthreads();
    f32x4 invl[6];
#pragma unroll
    for (int t = 0; t < 6; t++) {
        const int s = w + 12 * t;
        invl[t] = (f32x4){0.f, 0.f, 0.f, 0.f};
        if (s < 64) {
#pragma unroll
            for (int r = 0; r < 4; r++) {
                const f32x4 v4 = *(const f32x4*)&red[(((s >> 2) * 16) + quad * 4 + r) * 4];
                invl[t][r] = 1.f / (v4[0] + v4[1] + v4[2] + v4[3]);
            }
        }
    }

    // ---------------- pass 2: mix -> softmax -> mix -> PV ----------------
    f32x4 oacc[4];
#pragma unroll
    for (int nt = 0; nt < 4; nt++) oacc[nt] = (f32x4){0.f, 0.f, 0.f, 0.f};

    for (int jt = 0; jt < 16; jt++) {
        const int j0 = jt * 64;
        f32x4 sc[4];
#pragma unroll
        for (int nt = 0; nt < 4; nt++) {
            f32x4 a = (f32x4){0.f, 0.f, 0.f, 0.f};
#pragma unroll
            for (int kc = 0; kc < 2; kc++) {
                u32x4 bfr = *(const u32x4*)(kh + (size_t)(j0 + nt * 16 + l15) * 64 + kc * 32 + quad * 8);
                a = mfma16(aq[kc], bfr, a);
            }
            sc[nt] = a;
        }
        __syncthreads();   // b1: prior jt's SP reads + Abuf PV reads done
#pragma unroll
        for (int nt = 0; nt < 4; nt++)
#pragma unroll
            for (int r = 0; r < 4; r++)
                SP[((quad * 4 + r) * 64 + nt * 16 + l15) * 18 + w] = f2bf(sc[nt][r] * 0.125f);
        __syncthreads();   // b2: scores visible
#pragma unroll
        for (int t = 0; t < 6; t++) {
            const int s = w + 12 * t;
            if (s < 64) {
                const int row = s * 16 + l15, i = s >> 2, jq = s & 3;
                u32x4 bfr = (u32x4){0, 0, 0, 0};
                if (quad < 2) {
                    const u32* p = SP32 + row * 9 + quad * 4;
                    bfr[0] = p[0]; bfr[1] = p[1]; bfr[2] = p[2]; bfr[3] = p[3];
                }
                f32x4 d = mfma16(apre, bfr, (f32x4){0.f, 0.f, 0.f, 0.f});
                // probs (bf16) back into the same wave-exclusive rows, cols quad*4..+4
                u16 p0 = f2bf(__expf(d[0]) * invl[t][0]);
                u16 p1 = f2bf(__expf(d[1]) * invl[t][1]);
                u16 p2 = f2bf(__expf(d[2]) * invl[t][2]);
                u16 p3 = f2bf(__expf(d[3]) * invl[t][3]);
                SP32[row * 9 + quad * 2]     = (u32)p0 | ((u32)p1 << 16);
                SP32[row * 9 + quad * 2 + 1] = (u32)p2 | ((u32)p3 << 16);
                __asm__ volatile("s_waitcnt lgkmcnt(0)" ::: "memory");  // same-wave RAW
                u32x4 bfp = (u32x4){0, 0, 0, 0};
                if (quad < 2) {
                    const u32* p = SP32 + row * 9 + quad * 4;
                    bfp[0] = p[0]; bfp[1] = p[1]; bfp[2] = p[2]; bfp[3] = p[3];
                }
                f32x4 am = mfma16(apost, bfp, (f32x4){0.f, 0.f, 0.f, 0.f});
#pragma unroll
                for (int r = 0; r < 4; r++) {
                    const int g2 = quad * 4 + r;
                    if (g2 < 12)
                        Abuf[g2 * 1160 + i * 72 + jq * 16 + l15] = f2bf(am[r]);
                }
            }
        }
        __syncthreads();   // b3: amix visible
#pragma unroll
        for (int kc = 0; kc < 2; kc++) {
            u32x4 af = *(const u32x4*)&Abuf[w * 1160 + l15 * 72 + kc * 32 + quad * 8];
#pragma unroll
            for (int nt = 0; nt < 4; nt++) {
                u32x4 vf = *(const u32x4*)(vh + (size_t)(nt * 16 + l15) * 1024 + j0 + kc * 32 + quad * 8);
                oacc[nt] = mfma16(af, vf, oacc[nt]);
            }
        }
    }
#pragma unroll
    for (int nt = 0; nt < 4; nt++)
#pragma unroll
        for (int r = 0; r < 4; r++)
            ob[((size_t)b * 1024 + i0 + quad * 4 + r) * 768 + w * 64 + nt * 16 + l15] =
                f2bf(oacc[nt][r]);
}

// =====================================================================
extern "C" void kernel_launch(void* const* d_in, const int* in_sizes, int n_in,
                              void* d_out, int out_size, void* d_ws, size_t ws_size,
                              hipStream_t stream)
{
    float* out = (float*)d_out;

    u32* flag = (u32*)d_ws;
    u16* base = (u16*)d_ws + 128;
    u16* WT   = base;
    u16* WoT  = WT  + 2304 * 768;
    u16* qb   = WoT + 768 * 768;
    u16* kb   = qb  + 6291456;
    u16* vtb  = kb  + 6291456;
    u16* obuf = vtb + 6291456;
    u16* vb   = obuf;

    k_detect     <<<dim3(1), 64,  0, stream>>>((const u16*)d_in[0], flag);
    k_transpose_w<<<dim3(12, 24, 3), 256, 0, stream>>>(d_in[1], d_in[2], d_in[5], WT, WoT, flag);
    k_gemm_qkv   <<<dim3(36, 128),   256, 0, stream>>>(d_in[0], WT, qb, kb, vb, flag);
    k_transpose_v<<<dim3(16, 1, 96), 256, 0, stream>>>(vb, vtb);
    k_attn       <<<dim3(64, 8),     768, 0, stream>>>(qb, kb, vtb, d_in[3], d_in[4], obuf, flag);
    k_gemm_out   <<<dim3(12, 128),   256, 0, stream>>>(obuf, WoT, d_in[6], out, flag);
}